// Round 3
// baseline (102.351 us; speedup 1.0000x reference)
//
#include <hip/hip_runtime.h>

#define N_NODES 50000
#define N_EDGES 800000
#define D_FEAT  96
#define F4      (D_FEAT / 4)   // 24 float4 groups per row
#define ROWS_PER_BLOCK 16
#define BLOCK (ROWS_PER_BLOCK * F4)  // 384

// Fused kernel: threads 0..16 binary-search the block's 17 row bounds
// (rows is sorted COO row index) into LDS, then one thread per
// (row, float4-group) accumulates its row segment with 8-deep unrolled
// gathers for memory-level parallelism.
__global__ __launch_bounds__(BLOCK) void spmm_fused_kernel(
    const int*   __restrict__ rows,
    const int*   __restrict__ cols,
    const float* __restrict__ vals,
    const float* __restrict__ embeds,
    float*       __restrict__ out) {
    __shared__ int s_ptr[ROWS_PER_BLOCK + 1];

    const int tid      = threadIdx.x;
    const int row_base = blockIdx.x * ROWS_PER_BLOCK;

    // Build row_ptr slice: lower_bound(rows, row_base + tid)
    if (tid <= ROWS_PER_BLOCK) {
        int target = row_base + tid;
        int lo = 0, hi = N_EDGES;
        if (target >= N_NODES) {
            lo = N_EDGES;
        } else {
            while (lo < hi) {
                int mid = (lo + hi) >> 1;
                if (rows[mid] < target) lo = mid + 1;
                else hi = mid;
            }
        }
        s_ptr[tid] = lo;
    }
    __syncthreads();

    const int local_row = tid / F4;              // 0..15
    const int fg        = tid - local_row * F4;  // 0..23
    const int r         = row_base + local_row;
    if (r >= N_NODES) return;

    const float4* __restrict__ emb4 = (const float4*)embeds;

    int e   = s_ptr[local_row];
    int end = s_ptr[local_row + 1];

    float4 acc[4];
    acc[0] = make_float4(0.f, 0.f, 0.f, 0.f);
    acc[1] = acc[0]; acc[2] = acc[0]; acc[3] = acc[0];

    // 8-deep unroll: 8 independent gathers in flight per lane.
    for (; e + 7 < end; e += 8) {
        int   c[8];
        float v[8];
#pragma unroll
        for (int k = 0; k < 8; ++k) {
            c[k] = __builtin_nontemporal_load(&cols[e + k]);
            v[k] = __builtin_nontemporal_load(&vals[e + k]);
        }
        float4 m[8];
#pragma unroll
        for (int k = 0; k < 8; ++k) {
            m[k] = emb4[(size_t)c[k] * F4 + fg];
        }
#pragma unroll
        for (int k = 0; k < 8; ++k) {
            acc[k & 3].x += v[k] * m[k].x;
            acc[k & 3].y += v[k] * m[k].y;
            acc[k & 3].z += v[k] * m[k].z;
            acc[k & 3].w += v[k] * m[k].w;
        }
    }
    // Tail (up to 7 edges), keep 4 independent chains.
    for (int k = 0; e < end; ++e, ++k) {
        int   c = __builtin_nontemporal_load(&cols[e]);
        float v = __builtin_nontemporal_load(&vals[e]);
        float4 m = emb4[(size_t)c * F4 + fg];
        acc[k & 3].x += v * m.x;
        acc[k & 3].y += v * m.y;
        acc[k & 3].z += v * m.z;
        acc[k & 3].w += v * m.w;
    }

    float4 s;
    s.x = (acc[0].x + acc[1].x) + (acc[2].x + acc[3].x);
    s.y = (acc[0].y + acc[1].y) + (acc[2].y + acc[3].y);
    s.z = (acc[0].z + acc[1].z) + (acc[2].z + acc[3].z);
    s.w = (acc[0].w + acc[1].w) + (acc[2].w + acc[3].w);
    ((float4*)out)[(size_t)r * F4 + fg] = s;
}

extern "C" void kernel_launch(void* const* d_in, const int* in_sizes, int n_in,
                              void* d_out, int out_size, void* d_ws, size_t ws_size,
                              hipStream_t stream) {
    const int*   rows   = (const int*)  d_in[0];
    const int*   cols   = (const int*)  d_in[1];
    const float* vals   = (const float*)d_in[2];
    const float* embeds = (const float*)d_in[3];
    float*       out    = (float*)      d_out;

    int blocks = (N_NODES + ROWS_PER_BLOCK - 1) / ROWS_PER_BLOCK;  // 3125
    spmm_fused_kernel<<<blocks, BLOCK, 0, stream>>>(rows, cols, vals,
                                                    embeds, out);
}

// Round 4
// 84.923 us; speedup vs baseline: 1.2052x; 1.2052x over previous
//
#include <hip/hip_runtime.h>

#define N_NODES 50000
#define N_EDGES 800000
#define D_FEAT  96
#define F4      (D_FEAT / 4)   // 24 float4 groups per row
#define ROWS_PER_BLOCK 16
#define BLOCK (ROWS_PER_BLOCK * F4)  // 384

// Fused kernel: threads 0..16 binary-search the block's 17 row bounds into
// LDS, then one thread per (row, float4-group) accumulates its row segment.
// 8-deep unroll with NAMED scalars (not arrays!) so all temporaries live in
// VGPRs — round 3 proved indexed local arrays get demoted to LDS (25 KB,
// 7.4M bank conflicts, 2.4x slowdown).
__global__ __launch_bounds__(BLOCK) void spmm_fused_kernel(
    const int*   __restrict__ rows,
    const int*   __restrict__ cols,
    const float* __restrict__ vals,
    const float* __restrict__ embeds,
    float*       __restrict__ out) {
    __shared__ int s_ptr[ROWS_PER_BLOCK + 1];

    const int tid      = threadIdx.x;
    const int row_base = blockIdx.x * ROWS_PER_BLOCK;

    if (tid <= ROWS_PER_BLOCK) {
        int target = row_base + tid;
        int lo = 0, hi = N_EDGES;
        if (target >= N_NODES) {
            lo = N_EDGES;
        } else {
            while (lo < hi) {
                int mid = (lo + hi) >> 1;
                if (rows[mid] < target) lo = mid + 1;
                else hi = mid;
            }
        }
        s_ptr[tid] = lo;
    }
    __syncthreads();

    const int local_row = tid / F4;              // 0..15
    const int fg        = tid - local_row * F4;  // 0..23
    const int r         = row_base + local_row;
    if (r >= N_NODES) return;

    const float4* __restrict__ emb4 = (const float4*)embeds;

    int e   = s_ptr[local_row];
    int end = s_ptr[local_row + 1];

    float4 acc0 = make_float4(0.f, 0.f, 0.f, 0.f);
    float4 acc1 = acc0, acc2 = acc0, acc3 = acc0;

    // 8-deep unroll: 8 independent gathers in flight per lane, all named
    // scalars -> guaranteed VGPR allocation.
    for (; e + 7 < end; e += 8) {
        int c0 = __builtin_nontemporal_load(&cols[e + 0]);
        int c1 = __builtin_nontemporal_load(&cols[e + 1]);
        int c2 = __builtin_nontemporal_load(&cols[e + 2]);
        int c3 = __builtin_nontemporal_load(&cols[e + 3]);
        int c4 = __builtin_nontemporal_load(&cols[e + 4]);
        int c5 = __builtin_nontemporal_load(&cols[e + 5]);
        int c6 = __builtin_nontemporal_load(&cols[e + 6]);
        int c7 = __builtin_nontemporal_load(&cols[e + 7]);
        float v0 = __builtin_nontemporal_load(&vals[e + 0]);
        float v1 = __builtin_nontemporal_load(&vals[e + 1]);
        float v2 = __builtin_nontemporal_load(&vals[e + 2]);
        float v3 = __builtin_nontemporal_load(&vals[e + 3]);
        float v4 = __builtin_nontemporal_load(&vals[e + 4]);
        float v5 = __builtin_nontemporal_load(&vals[e + 5]);
        float v6 = __builtin_nontemporal_load(&vals[e + 6]);
        float v7 = __builtin_nontemporal_load(&vals[e + 7]);

        float4 m0 = emb4[(size_t)c0 * F4 + fg];
        float4 m1 = emb4[(size_t)c1 * F4 + fg];
        float4 m2 = emb4[(size_t)c2 * F4 + fg];
        float4 m3 = emb4[(size_t)c3 * F4 + fg];
        float4 m4 = emb4[(size_t)c4 * F4 + fg];
        float4 m5 = emb4[(size_t)c5 * F4 + fg];
        float4 m6 = emb4[(size_t)c6 * F4 + fg];
        float4 m7 = emb4[(size_t)c7 * F4 + fg];

        acc0.x += v0 * m0.x; acc0.y += v0 * m0.y; acc0.z += v0 * m0.z; acc0.w += v0 * m0.w;
        acc1.x += v1 * m1.x; acc1.y += v1 * m1.y; acc1.z += v1 * m1.z; acc1.w += v1 * m1.w;
        acc2.x += v2 * m2.x; acc2.y += v2 * m2.y; acc2.z += v2 * m2.z; acc2.w += v2 * m2.w;
        acc3.x += v3 * m3.x; acc3.y += v3 * m3.y; acc3.z += v3 * m3.z; acc3.w += v3 * m3.w;
        acc0.x += v4 * m4.x; acc0.y += v4 * m4.y; acc0.z += v4 * m4.z; acc0.w += v4 * m4.w;
        acc1.x += v5 * m5.x; acc1.y += v5 * m5.y; acc1.z += v5 * m5.z; acc1.w += v5 * m5.w;
        acc2.x += v6 * m6.x; acc2.y += v6 * m6.y; acc2.z += v6 * m6.z; acc2.w += v6 * m6.w;
        acc3.x += v7 * m7.x; acc3.y += v7 * m7.y; acc3.z += v7 * m7.z; acc3.w += v7 * m7.w;
    }
    // Tail: up to 7 edges, rotate over the 4 accumulator chains.
    int k = 0;
    for (; e < end; ++e, ++k) {
        int   c = __builtin_nontemporal_load(&cols[e]);
        float v = __builtin_nontemporal_load(&vals[e]);
        float4 m = emb4[(size_t)c * F4 + fg];
        if ((k & 3) == 0)      { acc0.x += v * m.x; acc0.y += v * m.y; acc0.z += v * m.z; acc0.w += v * m.w; }
        else if ((k & 3) == 1) { acc1.x += v * m.x; acc1.y += v * m.y; acc1.z += v * m.z; acc1.w += v * m.w; }
        else if ((k & 3) == 2) { acc2.x += v * m.x; acc2.y += v * m.y; acc2.z += v * m.z; acc2.w += v * m.w; }
        else                   { acc3.x += v * m.x; acc3.y += v * m.y; acc3.z += v * m.z; acc3.w += v * m.w; }
    }

    float4 s;
    s.x = (acc0.x + acc1.x) + (acc2.x + acc3.x);
    s.y = (acc0.y + acc1.y) + (acc2.y + acc3.y);
    s.z = (acc0.z + acc1.z) + (acc2.z + acc3.z);
    s.w = (acc0.w + acc1.w) + (acc2.w + acc3.w);
    ((float4*)out)[(size_t)r * F4 + fg] = s;
}

extern "C" void kernel_launch(void* const* d_in, const int* in_sizes, int n_in,
                              void* d_out, int out_size, void* d_ws, size_t ws_size,
                              hipStream_t stream) {
    const int*   rows   = (const int*)  d_in[0];
    const int*   cols   = (const int*)  d_in[1];
    const float* vals   = (const float*)d_in[2];
    const float* embeds = (const float*)d_in[3];
    float*       out    = (float*)      d_out;

    int blocks = (N_NODES + ROWS_PER_BLOCK - 1) / ROWS_PER_BLOCK;  // 3125
    spmm_fused_kernel<<<blocks, BLOCK, 0, stream>>>(rows, cols, vals,
                                                    embeds, out);
}

// Round 5
// 53.539 us; speedup vs baseline: 1.9117x; 1.5862x over previous
//
#include <hip/hip_runtime.h>

#define N_NODES 50000
#define N_EDGES 800000
#define D_FEAT  96
#define F4      (D_FEAT / 4)   // 24 float4 groups per row
#define ROWS_PER_BLOCK 16
#define BLOCK (ROWS_PER_BLOCK * F4)  // 384

// Kernel 1: build CSR row_ptr from sorted COO rows via binary search.
// Separate kernel: keeps the 20-step dependent search chain OFF the spmm
// blocks' critical path (round 4 fused it -> 2x regression from barrier idle).
__global__ void build_row_ptr_kernel(const int* __restrict__ rows,
                                     int* __restrict__ row_ptr) {
    int r = blockIdx.x * blockDim.x + threadIdx.x;
    if (r > N_NODES) return;
    int lo = 0, hi = N_EDGES;
    while (lo < hi) {
        int mid = (lo + hi) >> 1;
        if (rows[mid] < r) lo = mid + 1;
        else hi = mid;
    }
    row_ptr[r] = lo;
}

// Kernel 2: one thread per (row, float4-group). 24 threads/row, 16 rows per
// 384-thread block. 8-deep unroll with NAMED scalars (VGPR-resident — round 3
// proved indexed arrays demote to LDS). launch_bounds(384,2) lifts the VGPR
// cap to 256 so all 8 gathers can be in flight.
__global__ __launch_bounds__(BLOCK, 2) void spmm_csr_kernel(
    const int*   __restrict__ cols,
    const float* __restrict__ vals,
    const float* __restrict__ embeds,
    const int*   __restrict__ row_ptr,
    float*       __restrict__ out) {
    const int tid       = threadIdx.x;
    const int local_row = tid / F4;              // 0..15
    const int fg        = tid - local_row * F4;  // 0..23
    const int r         = blockIdx.x * ROWS_PER_BLOCK + local_row;
    if (r >= N_NODES) return;

    const float4* __restrict__ emb4 = (const float4*)embeds;

    int e   = row_ptr[r];
    int end = row_ptr[r + 1];

    float4 acc0 = make_float4(0.f, 0.f, 0.f, 0.f);
    float4 acc1 = acc0, acc2 = acc0, acc3 = acc0;

    // 8-deep: 8 independent gathers in flight per lane.
    for (; e + 7 < end; e += 8) {
        int c0 = cols[e + 0], c1 = cols[e + 1], c2 = cols[e + 2], c3 = cols[e + 3];
        int c4 = cols[e + 4], c5 = cols[e + 5], c6 = cols[e + 6], c7 = cols[e + 7];
        float v0 = vals[e + 0], v1 = vals[e + 1], v2 = vals[e + 2], v3 = vals[e + 3];
        float v4 = vals[e + 4], v5 = vals[e + 5], v6 = vals[e + 6], v7 = vals[e + 7];

        float4 m0 = emb4[c0 * F4 + fg];
        float4 m1 = emb4[c1 * F4 + fg];
        float4 m2 = emb4[c2 * F4 + fg];
        float4 m3 = emb4[c3 * F4 + fg];
        float4 m4 = emb4[c4 * F4 + fg];
        float4 m5 = emb4[c5 * F4 + fg];
        float4 m6 = emb4[c6 * F4 + fg];
        float4 m7 = emb4[c7 * F4 + fg];

        acc0.x += v0 * m0.x; acc0.y += v0 * m0.y; acc0.z += v0 * m0.z; acc0.w += v0 * m0.w;
        acc1.x += v1 * m1.x; acc1.y += v1 * m1.y; acc1.z += v1 * m1.z; acc1.w += v1 * m1.w;
        acc2.x += v2 * m2.x; acc2.y += v2 * m2.y; acc2.z += v2 * m2.z; acc2.w += v2 * m2.w;
        acc3.x += v3 * m3.x; acc3.y += v3 * m3.y; acc3.z += v3 * m3.z; acc3.w += v3 * m3.w;
        acc0.x += v4 * m4.x; acc0.y += v4 * m4.y; acc0.z += v4 * m4.z; acc0.w += v4 * m4.w;
        acc1.x += v5 * m5.x; acc1.y += v5 * m5.y; acc1.z += v5 * m5.z; acc1.w += v5 * m5.w;
        acc2.x += v6 * m6.x; acc2.y += v6 * m6.y; acc2.z += v6 * m6.z; acc2.w += v6 * m6.w;
        acc3.x += v7 * m7.x; acc3.y += v7 * m7.y; acc3.z += v7 * m7.z; acc3.w += v7 * m7.w;
    }
    // 4-deep mid-tail.
    if (e + 3 < end) {
        int c0 = cols[e + 0], c1 = cols[e + 1], c2 = cols[e + 2], c3 = cols[e + 3];
        float v0 = vals[e + 0], v1 = vals[e + 1], v2 = vals[e + 2], v3 = vals[e + 3];
        float4 m0 = emb4[c0 * F4 + fg];
        float4 m1 = emb4[c1 * F4 + fg];
        float4 m2 = emb4[c2 * F4 + fg];
        float4 m3 = emb4[c3 * F4 + fg];
        acc0.x += v0 * m0.x; acc0.y += v0 * m0.y; acc0.z += v0 * m0.z; acc0.w += v0 * m0.w;
        acc1.x += v1 * m1.x; acc1.y += v1 * m1.y; acc1.z += v1 * m1.z; acc1.w += v1 * m1.w;
        acc2.x += v2 * m2.x; acc2.y += v2 * m2.y; acc2.z += v2 * m2.z; acc2.w += v2 * m2.w;
        acc3.x += v3 * m3.x; acc3.y += v3 * m3.y; acc3.z += v3 * m3.z; acc3.w += v3 * m3.w;
        e += 4;
    }
    // Scalar tail (<=3 edges).
    for (; e < end; ++e) {
        int   c = cols[e];
        float v = vals[e];
        float4 m = emb4[c * F4 + fg];
        acc0.x += v * m.x; acc0.y += v * m.y; acc0.z += v * m.z; acc0.w += v * m.w;
    }

    float4 s;
    s.x = (acc0.x + acc1.x) + (acc2.x + acc3.x);
    s.y = (acc0.y + acc1.y) + (acc2.y + acc3.y);
    s.z = (acc0.z + acc1.z) + (acc2.z + acc3.z);
    s.w = (acc0.w + acc1.w) + (acc2.w + acc3.w);
    ((float4*)out)[r * F4 + fg] = s;
}

extern "C" void kernel_launch(void* const* d_in, const int* in_sizes, int n_in,
                              void* d_out, int out_size, void* d_ws, size_t ws_size,
                              hipStream_t stream) {
    const int*   rows   = (const int*)  d_in[0];
    const int*   cols   = (const int*)  d_in[1];
    const float* vals   = (const float*)d_in[2];
    const float* embeds = (const float*)d_in[3];
    float*       out    = (float*)      d_out;

    int* row_ptr = (int*)d_ws;  // (N_NODES+1) ints

    {
        int threads = 256;
        int blocks  = (N_NODES + 1 + threads - 1) / threads;
        build_row_ptr_kernel<<<blocks, threads, 0, stream>>>(rows, row_ptr);
    }
    {
        int blocks = (N_NODES + ROWS_PER_BLOCK - 1) / ROWS_PER_BLOCK;  // 3125
        spmm_csr_kernel<<<blocks, BLOCK, 0, stream>>>(cols, vals, embeds,
                                                      row_ptr, out);
    }
}

// Round 6
// 49.562 us; speedup vs baseline: 2.0651x; 1.0802x over previous
//
#include <hip/hip_runtime.h>

#define N_NODES 50000
#define N_EDGES 800000
#define D_FEAT  96
#define F8      (D_FEAT / 8)          // 12 ushort8 (16B) groups per bf16 row
#define ROWS_PER_BLOCK 32
#define BLOCK (ROWS_PER_BLOCK * F8)   // 384

#define N_CVT  (N_NODES * D_FEAT / 8) // 600000 convert threads (8 floats each)
#define EMB_OFF 200192                // row_ptr region (200004 B) rounded to 256
#define WS_NEEDED (EMB_OFF + (size_t)N_NODES * D_FEAT * 2)

__device__ inline unsigned int f2bf(float f) {  // RNE f32->bf16, result in low 16
    unsigned u = __float_as_uint(f);
    return (u + 0x7fffu + ((u >> 16) & 1u)) >> 16;
}

// Prep kernel (no barriers): converts embeds f32->bf16 into ws, and the first
// 50001 threads also binary-search row_ptr. Off the spmm critical path.
__global__ void prep_kernel(const int* __restrict__ rows,
                            const float* __restrict__ embeds,
                            unsigned int* __restrict__ emb_bf,   // uint = 2 bf16
                            int* __restrict__ row_ptr) {
    int idx = blockIdx.x * blockDim.x + threadIdx.x;
    if (idx < N_CVT) {
        const float4* src = (const float4*)embeds;
        float4 a = src[idx * 2 + 0];
        float4 b = src[idx * 2 + 1];
        uint4 p;
        p.x = f2bf(a.x) | (f2bf(a.y) << 16);
        p.y = f2bf(a.z) | (f2bf(a.w) << 16);
        p.z = f2bf(b.x) | (f2bf(b.y) << 16);
        p.w = f2bf(b.z) | (f2bf(b.w) << 16);
        ((uint4*)emb_bf)[idx] = p;
    }
    if (idx <= N_NODES) {
        int lo = 0, hi = N_EDGES;
        while (lo < hi) {
            int mid = (lo + hi) >> 1;
            if (rows[mid] < idx) lo = mid + 1;
            else hi = mid;
        }
        row_ptr[idx] = lo;
    }
}

// Unpack uint4 (8 bf16) and fmac into two float4 accumulators.
#define ACCUM(mm, vv, A, B) {                                   \
    float f0 = __uint_as_float((mm).x << 16);                   \
    float f1 = __uint_as_float((mm).x & 0xffff0000u);           \
    float f2 = __uint_as_float((mm).y << 16);                   \
    float f3 = __uint_as_float((mm).y & 0xffff0000u);           \
    float f4 = __uint_as_float((mm).z << 16);                   \
    float f5 = __uint_as_float((mm).z & 0xffff0000u);           \
    float f6 = __uint_as_float((mm).w << 16);                   \
    float f7 = __uint_as_float((mm).w & 0xffff0000u);           \
    A.x += (vv) * f0; A.y += (vv) * f1; A.z += (vv) * f2; A.w += (vv) * f3; \
    B.x += (vv) * f4; B.y += (vv) * f5; B.z += (vv) * f6; B.w += (vv) * f7; }

// SpMM over bf16 embeds: 12 threads/row (16B ushort8 gathers), 32 rows/block.
// Halves gather requests AND bytes vs f32/float4. Named scalars only.
__global__ __launch_bounds__(BLOCK, 2) void spmm_bf16_kernel(
    const int*          __restrict__ cols,
    const float*        __restrict__ vals,
    const unsigned int* __restrict__ emb_bf,
    const int*          __restrict__ row_ptr,
    float*              __restrict__ out) {
    const int tid       = threadIdx.x;
    const int local_row = tid / F8;               // 0..31
    const int fg        = tid - local_row * F8;   // 0..11
    const int r         = blockIdx.x * ROWS_PER_BLOCK + local_row;
    if (r >= N_NODES) return;

    const uint4* __restrict__ emb = (const uint4*)emb_bf;

    int e   = row_ptr[r];
    int end = row_ptr[r + 1];

    float4 accA0 = make_float4(0.f, 0.f, 0.f, 0.f);
    float4 accB0 = accA0, accA1 = accA0, accB1 = accA0;

    for (; e + 7 < end; e += 8) {
        int c0 = cols[e + 0], c1 = cols[e + 1], c2 = cols[e + 2], c3 = cols[e + 3];
        int c4 = cols[e + 4], c5 = cols[e + 5], c6 = cols[e + 6], c7 = cols[e + 7];
        float v0 = vals[e + 0], v1 = vals[e + 1], v2 = vals[e + 2], v3 = vals[e + 3];
        float v4 = vals[e + 4], v5 = vals[e + 5], v6 = vals[e + 6], v7 = vals[e + 7];

        uint4 m0 = emb[(size_t)c0 * F8 + fg];
        uint4 m1 = emb[(size_t)c1 * F8 + fg];
        uint4 m2 = emb[(size_t)c2 * F8 + fg];
        uint4 m3 = emb[(size_t)c3 * F8 + fg];
        uint4 m4 = emb[(size_t)c4 * F8 + fg];
        uint4 m5 = emb[(size_t)c5 * F8 + fg];
        uint4 m6 = emb[(size_t)c6 * F8 + fg];
        uint4 m7 = emb[(size_t)c7 * F8 + fg];

        ACCUM(m0, v0, accA0, accB0);
        ACCUM(m1, v1, accA1, accB1);
        ACCUM(m2, v2, accA0, accB0);
        ACCUM(m3, v3, accA1, accB1);
        ACCUM(m4, v4, accA0, accB0);
        ACCUM(m5, v5, accA1, accB1);
        ACCUM(m6, v6, accA0, accB0);
        ACCUM(m7, v7, accA1, accB1);
    }
    if (e + 3 < end) {
        int c0 = cols[e + 0], c1 = cols[e + 1], c2 = cols[e + 2], c3 = cols[e + 3];
        float v0 = vals[e + 0], v1 = vals[e + 1], v2 = vals[e + 2], v3 = vals[e + 3];
        uint4 m0 = emb[(size_t)c0 * F8 + fg];
        uint4 m1 = emb[(size_t)c1 * F8 + fg];
        uint4 m2 = emb[(size_t)c2 * F8 + fg];
        uint4 m3 = emb[(size_t)c3 * F8 + fg];
        ACCUM(m0, v0, accA0, accB0);
        ACCUM(m1, v1, accA1, accB1);
        ACCUM(m2, v2, accA0, accB0);
        ACCUM(m3, v3, accA1, accB1);
        e += 4;
    }
    for (; e < end; ++e) {
        int   c = cols[e];
        float v = vals[e];
        uint4 m = emb[(size_t)c * F8 + fg];
        ACCUM(m, v, accA0, accB0);
    }

    float4 sA, sB;
    sA.x = accA0.x + accA1.x; sA.y = accA0.y + accA1.y;
    sA.z = accA0.z + accA1.z; sA.w = accA0.w + accA1.w;
    sB.x = accB0.x + accB1.x; sB.y = accB0.y + accB1.y;
    sB.z = accB0.z + accB1.z; sB.w = accB0.w + accB1.w;
    float4* o = (float4*)out;
    o[(size_t)r * 24 + fg * 2 + 0] = sA;   // features fg*8 .. fg*8+3
    o[(size_t)r * 24 + fg * 2 + 1] = sB;   // features fg*8+4 .. fg*8+7
}

// ---------- fallback f32 path (proven round-2/5 structure) ----------
#define F4 (D_FEAT / 4)
__global__ __launch_bounds__(384, 2) void spmm_f32_kernel(
    const int*   __restrict__ cols,
    const float* __restrict__ vals,
    const float* __restrict__ embeds,
    const int*   __restrict__ row_ptr,
    float*       __restrict__ out) {
    const int tid       = threadIdx.x;
    const int local_row = tid / F4;
    const int fg        = tid - local_row * F4;
    const int r         = blockIdx.x * 16 + local_row;
    if (r >= N_NODES) return;
    const float4* __restrict__ emb4 = (const float4*)embeds;
    int e = row_ptr[r], end = row_ptr[r + 1];
    float4 a0 = make_float4(0.f, 0.f, 0.f, 0.f), a1 = a0, a2 = a0, a3 = a0;
    for (; e + 3 < end; e += 4) {
        int c0 = cols[e], c1 = cols[e + 1], c2 = cols[e + 2], c3 = cols[e + 3];
        float v0 = vals[e], v1 = vals[e + 1], v2 = vals[e + 2], v3 = vals[e + 3];
        float4 m0 = emb4[c0 * F4 + fg], m1 = emb4[c1 * F4 + fg];
        float4 m2 = emb4[c2 * F4 + fg], m3 = emb4[c3 * F4 + fg];
        a0.x += v0 * m0.x; a0.y += v0 * m0.y; a0.z += v0 * m0.z; a0.w += v0 * m0.w;
        a1.x += v1 * m1.x; a1.y += v1 * m1.y; a1.z += v1 * m1.z; a1.w += v1 * m1.w;
        a2.x += v2 * m2.x; a2.y += v2 * m2.y; a2.z += v2 * m2.z; a2.w += v2 * m2.w;
        a3.x += v3 * m3.x; a3.y += v3 * m3.y; a3.z += v3 * m3.z; a3.w += v3 * m3.w;
    }
    for (; e < end; ++e) {
        int c = cols[e]; float v = vals[e];
        float4 m = emb4[c * F4 + fg];
        a0.x += v * m.x; a0.y += v * m.y; a0.z += v * m.z; a0.w += v * m.w;
    }
    float4 s;
    s.x = (a0.x + a1.x) + (a2.x + a3.x);
    s.y = (a0.y + a1.y) + (a2.y + a3.y);
    s.z = (a0.z + a1.z) + (a2.z + a3.z);
    s.w = (a0.w + a1.w) + (a2.w + a3.w);
    ((float4*)out)[r * F4 + fg] = s;
}

__global__ void build_row_ptr_kernel(const int* __restrict__ rows,
                                     int* __restrict__ row_ptr) {
    int r = blockIdx.x * blockDim.x + threadIdx.x;
    if (r > N_NODES) return;
    int lo = 0, hi = N_EDGES;
    while (lo < hi) {
        int mid = (lo + hi) >> 1;
        if (rows[mid] < r) lo = mid + 1;
        else hi = mid;
    }
    row_ptr[r] = lo;
}

extern "C" void kernel_launch(void* const* d_in, const int* in_sizes, int n_in,
                              void* d_out, int out_size, void* d_ws, size_t ws_size,
                              hipStream_t stream) {
    const int*   rows   = (const int*)  d_in[0];
    const int*   cols   = (const int*)  d_in[1];
    const float* vals   = (const float*)d_in[2];
    const float* embeds = (const float*)d_in[3];
    float*       out    = (float*)      d_out;

    int* row_ptr = (int*)d_ws;

    if (ws_size >= WS_NEEDED) {
        unsigned int* emb_bf = (unsigned int*)((char*)d_ws + EMB_OFF);
        {
            int threads = 256;
            int blocks  = (N_CVT + threads - 1) / threads;   // 2344
            prep_kernel<<<blocks, threads, 0, stream>>>(rows, embeds,
                                                        emb_bf, row_ptr);
        }
        {
            int blocks = (N_NODES + ROWS_PER_BLOCK - 1) / ROWS_PER_BLOCK; // 1563
            spmm_bf16_kernel<<<blocks, BLOCK, 0, stream>>>(cols, vals, emb_bf,
                                                           row_ptr, out);
        }
    } else {
        {
            int threads = 256;
            int blocks  = (N_NODES + 1 + threads - 1) / threads;
            build_row_ptr_kernel<<<blocks, threads, 0, stream>>>(rows, row_ptr);
        }
        {
            int blocks = (N_NODES + 15) / 16;
            spmm_f32_kernel<<<blocks, 384, 0, stream>>>(cols, vals, embeds,
                                                        row_ptr, out);
        }
    }
}